// Round 12
// baseline (128.467 us; speedup 1.0000x reference)
//
#include <hip/hip_runtime.h>
#include <hip/hip_bf16.h>
#include <math.h>

#define B 8
#define N 2048
#define C 16
#define HID 128
#define NRF 16384      // 128*128
#define MAXLEN 8
#define MAXCH 2048     // max chains per batch (<= N)

__device__ __forceinline__ float sigf(float x) { return 1.f / (1.f + expf(-x)); }

// ---------------- pre: per-batch build + sort + classify + transpose -------
// Blocks 0..7: one batch each, 1024 threads, counters in LDS (64 KB) -> no
// global init dependency, no cross-block atomics (R0/R1 lesson structural).
// Chain heads time-sort their slots here. Emits chainpk = ev0|len<<11 and
// TWO per-batch lists: mlist2 (len==2, quad-processed) and mlist3 (len>=3,
// serial). Blocks 8..80: weight transpose + bias (independent work).
__global__ __launch_bounds__(1024) void k_pre(
    const int* __restrict__ coords, const float* __restrict__ w_ih,
    const float* __restrict__ w_hh, const float* __restrict__ b_ih,
    const float* __restrict__ b_hh, float* __restrict__ w_ih_T,
    float* __restrict__ w_hh_T, float* __restrict__ biassum,
    int* __restrict__ map, int* __restrict__ cnt, int* __restrict__ m2cnt,
    int* __restrict__ m3cnt, int* __restrict__ chainpk,
    int* __restrict__ mlist2, int* __restrict__ mlist3,
    int* __restrict__ slots) {
    int tid = threadIdx.x;
    if (blockIdx.x < 8) {
        int bb = blockIdx.x;
        __shared__ int cnt_l[NRF];          // 64 KB
        __shared__ int nch_l, n2_l, n3_l;
#pragma unroll
        for (int i = 0; i < 16; i++) cnt_l[tid + 1024 * i] = 0;
        if (tid == 0) { nch_l = 0; n2_l = 0; n3_l = 0; }
#pragma unroll
        for (int i = 0; i < 16; i++) map[bb * NRF + tid + 1024 * i] = -1;
        __syncthreads();
        int n0 = tid, n1 = tid + 1024;
        int2 c0 = ((const int2*)coords)[bb * N + n0];
        int2 c1 = ((const int2*)coords)[bb * N + n1];
        int rf0 = c0.y * 128 + c0.x;
        int rf1 = c1.y * 128 + c1.x;
        int pos0 = atomicAdd(&cnt_l[rf0], 1);
        int pos1 = atomicAdd(&cnt_l[rf1], 1);
        if (pos0 < MAXLEN) slots[((size_t)bb * NRF + rf0) * MAXLEN + pos0] = n0;
        if (pos1 < MAXLEN) slots[((size_t)bb * NRF + rf1) * MAXLEN + pos1] = n1;
        __syncthreads();                    // counts + slot stores visible
#pragma unroll
        for (int e = 0; e < 2; e++) {
            int rf = e ? rf1 : rf0;
            int pos = e ? pos1 : pos0;
            if (pos == 0) {                 // chain head
                int j = atomicAdd(&nch_l, 1);            // LDS atomic
                int len = cnt_l[rf];
                if (len > MAXLEN) len = MAXLEN;
                map[bb * NRF + rf] = j;
                int* sl = slots + ((size_t)bb * NRF + rf) * MAXLEN;
                int ev[MAXLEN];
#pragma unroll
                for (int t = 0; t < MAXLEN; t++) {
                    int v = sl[t];
                    ev[t] = (t < len) ? v : 0x7fffffff;
                }
#pragma unroll
                for (int a = 0; a < MAXLEN; a++)   // time-sort
#pragma unroll
                    for (int q = 0; q < MAXLEN - 1; q++) {
                        int u = ev[q], v = ev[q + 1];
                        ev[q] = min(u, v);
                        ev[q + 1] = max(u, v);
                    }
                if (len >= 2) {
                    for (int t = 0; t < len; t++) sl[t] = ev[t];
                    if (len == 2) {
                        int m = atomicAdd(&n2_l, 1);
                        if (m < 512) mlist2[bb * 512 + m] = j | (rf << 11);
                    } else {
                        int m = atomicAdd(&n3_l, 1);
                        if (m < 256) mlist3[bb * 256 + m] = j | (rf << 11);
                    }
                }
                chainpk[bb * MAXCH + j] = ev[0] | (len << 11);
            }
        }
        __syncthreads();
        if (tid == 0) {
            cnt[bb] = nch_l;
            m2cnt[bb] = (n2_l > 512) ? 512 : n2_l;
            m3cnt[bb] = (n3_l > 256) ? 256 : n3_l;
        }
    } else {
        int i = (blockIdx.x - 8) * 1024 + tid;   // 73 blocks cover 74240
        if (i < C * 512) {                 // w_ih_T[c][j] = w_ih[j][c]
            int c = i >> 9, j = i & 511;
            w_ih_T[i] = w_ih[j * C + c];
        }
        if (i < HID * 512) {               // w_hh_T[k][j] = w_hh[j][k]
            int k = i >> 9, j = i & 511;
            w_hh_T[i] = w_hh[j * HID + k];
        }
        if (i < 512) biassum[i] = b_ih[i] + b_hh[i];
    }
}

// ---------------- main: one dispatch, three DISJOINT block roles -----------
// Blocks 0..255:    len>=3 chains, serial, one block per chain (critical
//                   path first). ~45 chains total.
// Blocks 256..511:  len==2 chains, FOUR per block lock-step: one w_hh_T load
//                   feeds 4 FMAs (4x L2-traffic cut vs R11) while ~220
//                   blocks stay fully parallel (R5/R6/R9 lesson intact).
// Blocks 512..1535: singletons (gate0), 16 slots/block.
// LDS is a UNION pool (34.8 KB) -> 4 blocks/CU, 32 waves/CU.
__global__ __launch_bounds__(512) void k_main(
    const float* __restrict__ features, const float* __restrict__ w_ih_T,
    const float* __restrict__ w_hh_T, const float* __restrict__ biassum,
    const int* __restrict__ cnt, const int* __restrict__ chainpk,
    const int* __restrict__ m2cnt, const int* __restrict__ m3cnt,
    const int* __restrict__ mlist2, const int* __restrict__ mlist3,
    const int* __restrict__ slots, float* __restrict__ hfin) {
    __shared__ float pool[8704];           // 34.8 KB union
    __shared__ int meta[16];
    int tid = threadIdx.x;

    if (blockIdx.x < 256) {
        // ------------- serial recur: one block per len>=3 chain ------------
        int bb = blockIdx.x >> 5;          // 32 slots per batch
        int s0 = blockIdx.x & 31;
        int M3 = m3cnt[bb];
        if (s0 >= M3) return;
        float* h_s = pool;                 // [128]
        float* c_s = pool + 128;           // [128]
        float* x_s = pool + 256;           // [16]
        float* g_s = pool + 512;           // [512]
        float wi[16];
#pragma unroll
        for (int c2 = 0; c2 < 16; c2++) wi[c2] = w_ih_T[c2 * 512 + tid];
        float bs = biassum[tid];
        for (int m = s0; m < M3; m += 32) {    // typically 1 iteration
            int e = mlist3[bb * 256 + m];
            int j = e & 2047, rf = e >> 11;
            size_t idx = (size_t)(bb * MAXCH + j);
            int len = chainpk[bb * MAXCH + j] >> 11;
            const int* sl = slots + ((size_t)bb * NRF + rf) * MAXLEN;  // sorted
            if (tid < 16) x_s[tid] = features[((size_t)(bb * N + sl[0])) * C + tid];
            if (tid < 128) c_s[tid] = 0.f;
            __syncthreads();
            for (int t = 0; t < len; t++) {    // len block-uniform
                float a0 = bs, a1 = 0.f, a2 = 0.f, a3 = 0.f;
#pragma unroll
                for (int c2 = 0; c2 < 16; c2++) a0 += wi[c2] * x_s[c2];
                if (t > 0) {
#pragma unroll 8
                    for (int k = 0; k < 128; k += 4) {
                        a0 += w_hh_T[k * 512 + tid]       * h_s[k];
                        a1 += w_hh_T[(k + 1) * 512 + tid] * h_s[k + 1];
                        a2 += w_hh_T[(k + 2) * 512 + tid] * h_s[k + 2];
                        a3 += w_hh_T[(k + 3) * 512 + tid] * h_s[k + 3];
                    }
                }
                g_s[tid] = (a0 + a1) + (a2 + a3);
                __syncthreads();
                if (tid < 128) {
                    float ig = sigf(g_s[tid]);
                    float fg = sigf(g_s[tid + 128]);
                    float gg = tanhf(g_s[tid + 256]);
                    float og = sigf(g_s[tid + 384]);
                    float cn = fg * c_s[tid] + ig * gg;   // t=0: c=0
                    c_s[tid] = cn;
                    h_s[tid] = og * tanhf(cn);
                }
                if (tid < 16 && t + 1 < len)
                    x_s[tid] = features[((size_t)(bb * N + sl[t + 1])) * C + tid];
                __syncthreads();
            }
            if (tid < 128) hfin[idx * HID + tid] = h_s[tid];
            __syncthreads();
        }
    } else if (blockIdx.x < 512) {
        // ------------- quad recur: FOUR len==2 chains per block ------------
        int b2 = blockIdx.x - 256;
        int bb = b2 >> 5;                  // 32 quad-slots per batch
        int q0 = b2 & 31;
        int M2 = m2cnt[bb];
        if (q0 * 4 >= M2) return;
        float* x0 = pool;                  // [4][16]
        float* x1 = pool + 64;             // [4][16]
        float4* g4 = (float4*)(pool + 128);// [512] float4 (8 KB)
        float* h4 = pool + 2176;           // [4][128]
        float* c4 = pool + 2688;           // [4][128]
        float wi[16];
#pragma unroll
        for (int c2 = 0; c2 < 16; c2++) wi[c2] = w_ih_T[c2 * 512 + tid];
        float bs = biassum[tid];
        for (int g = q0; g * 4 < M2; g += 32) {   // typically 1 iteration
            if (tid < 4) {
                int m = g * 4 + tid;
                meta[tid] = (m < M2) ? mlist2[bb * 512 + m] : -1;
            }
            __syncthreads();
            if (tid < 128) {               // stage x0,x1 for 4 chains
                int which = tid >> 6, i = (tid >> 4) & 3, cc = tid & 15;
                int e = meta[i];
                if (e >= 0) {
                    int rf = e >> 11;
                    int ev = slots[((size_t)bb * NRF + rf) * MAXLEN + which];
                    pool[which * 64 + i * 16 + cc] =
                        features[((size_t)(bb * N + ev)) * C + cc];
                }
            }
            __syncthreads();
            {   // step 0 (c=0): thread = gate col tid, 4 chains
                float a0 = bs, a1 = bs, a2 = bs, a3 = bs;
#pragma unroll
                for (int c2 = 0; c2 < 16; c2++) {
                    float w = wi[c2];
                    a0 += w * x0[c2];
                    a1 += w * x0[16 + c2];
                    a2 += w * x0[32 + c2];
                    a3 += w * x0[48 + c2];
                }
                g4[tid] = make_float4(a0, a1, a2, a3);
            }
            __syncthreads();
            {   // act 0: thread = (chain i, hid)
                int i = tid >> 7, hid = tid & 127;
                float gi = ((float*)&g4[hid])[i];
                float gg = ((float*)&g4[hid + 256])[i];
                float go = ((float*)&g4[hid + 384])[i];
                float cn = sigf(gi) * tanhf(gg);
                c4[i * 128 + hid] = cn;
                h4[i * 128 + hid] = sigf(go) * tanhf(cn);
            }
            __syncthreads();
            {   // step 1: one w_hh load feeds 4 chains
                float a0 = bs, a1 = bs, a2 = bs, a3 = bs;
#pragma unroll
                for (int c2 = 0; c2 < 16; c2++) {
                    float w = wi[c2];
                    a0 += w * x1[c2];
                    a1 += w * x1[16 + c2];
                    a2 += w * x1[32 + c2];
                    a3 += w * x1[48 + c2];
                }
#pragma unroll 8
                for (int k = 0; k < 128; k++) {
                    float w = w_hh_T[k * 512 + tid];
                    a0 += w * h4[k];
                    a1 += w * h4[128 + k];
                    a2 += w * h4[256 + k];
                    a3 += w * h4[384 + k];
                }
                g4[tid] = make_float4(a0, a1, a2, a3);
            }
            __syncthreads();
            {   // act 1 + store
                int i = tid >> 7, hid = tid & 127;
                int e = meta[i];
                if (e >= 0) {
                    float gi = ((float*)&g4[hid])[i];
                    float gf = ((float*)&g4[hid + 128])[i];
                    float gg = ((float*)&g4[hid + 256])[i];
                    float go = ((float*)&g4[hid + 384])[i];
                    float cn = sigf(gf) * c4[i * 128 + hid] + sigf(gi) * tanhf(gg);
                    float hn = sigf(go) * tanhf(cn);
                    hfin[(size_t)(bb * MAXCH + (e & 2047)) * HID + hid] = hn;
                }
            }
            __syncthreads();
        }
    } else {
        // ------------- gate0: singletons only, 16 slots/block --------------
        int b2 = blockIdx.x - 512;
        int bb = b2 >> 7;                  // 128 blocks per batch
        int slot0 = (b2 & 127) * 16;
        float* ls_w = pool;                // [C*512] 32 KB
        float* ls_b = pool + 8192;         // [512]
        int nc = cnt[bb];
        if (tid < 16) {
            int j = slot0 + tid;
            meta[tid] = (j < nc) ? chainpk[bb * MAXCH + j] : -1;
        }
        for (int i = tid; i < C * 128; i += 512)       // float4 staging
            ((float4*)ls_w)[i] = ((const float4*)w_ih_T)[i];
        ls_b[tid] = biassum[tid];
        __syncthreads();
        int w = tid >> 6, lane = tid & 63;
        int pk[2];
        float f[2];
#pragma unroll
        for (int s2 = 0; s2 < 2; s2++) {   // issue all feature loads first
            pk[s2] = meta[w * 2 + s2];
            f[s2] = 0.f;
            if (pk[s2] >= 0 && (pk[s2] >> 11) == 1 && lane < 16)
                f[s2] = features[((size_t)(bb * N + (pk[s2] & 2047))) * C + lane];
        }
#pragma unroll
        for (int s2 = 0; s2 < 2; s2++) {
            if (pk[s2] < 0 || (pk[s2] >> 11) != 1) continue;  // multi handled above
            float ai0 = ls_b[lane],       ai1 = ls_b[lane + 64];
            float ag0 = ls_b[lane + 256], ag1 = ls_b[lane + 320];
            float ao0 = ls_b[lane + 384], ao1 = ls_b[lane + 448];
#pragma unroll
            for (int c2 = 0; c2 < 16; c2++) {
                float xv = __shfl(f[s2], c2, 64);
                ai0 += ls_w[c2 * 512 + lane]       * xv;
                ai1 += ls_w[c2 * 512 + lane + 64]  * xv;
                ag0 += ls_w[c2 * 512 + lane + 256] * xv;
                ag1 += ls_w[c2 * 512 + lane + 320] * xv;
                ao0 += ls_w[c2 * 512 + lane + 384] * xv;
                ao1 += ls_w[c2 * 512 + lane + 448] * xv;
            }
            float c0 = sigf(ai0) * tanhf(ag0);     // c_prev=0 -> f-gate dead
            float c1 = sigf(ai1) * tanhf(ag1);
            float h0 = sigf(ao0) * tanhf(c0);
            float h1 = sigf(ao1) * tanhf(c1);
            size_t idx = (size_t)(bb * MAXCH + slot0 + w * 2 + s2);
            hfin[idx * HID + lane] = h0;
            hfin[idx * HID + lane + 64] = h1;
        }
    }
}

// ---------------- scatter to dense [B, HID, 128, 128] ----------------
__global__ __launch_bounds__(256) void k_scatter(
    const float* __restrict__ hfin, const int* __restrict__ map,
    float* __restrict__ out) {
    int b = blockIdx.x >> 7;        // grid = B*128
    int y = blockIdx.x & 127;
    int t = threadIdx.x;
    int xq = t & 31;                // x quad: covers x = 4*xq .. 4*xq+3
    int hg = t >> 5;                // hid group 0..7 (16 hids each)
    const int4* mrow = (const int4*)(map + b * NRF + y * 128);
    int4 kk = mrow[xq];
    const float* hb = hfin + (size_t)b * MAXCH * HID;
#pragma unroll
    for (int hh = 0; hh < 16; hh++) {
        int hid = hg * 16 + hh;
        float4 v;
        v.x = (kk.x < 0) ? 0.f : hb[kk.x * HID + hid];
        v.y = (kk.y < 0) ? 0.f : hb[kk.y * HID + hid];
        v.z = (kk.z < 0) ? 0.f : hb[kk.z * HID + hid];
        v.w = (kk.w < 0) ? 0.f : hb[kk.w * HID + hid];
        *(float4*)(out + ((((size_t)b * HID + hid) * 128 + y) * 128) + xq * 4) = v;
    }
}

extern "C" void kernel_launch(void* const* d_in, const int* in_sizes, int n_in,
                              void* d_out, int out_size, void* d_ws, size_t ws_size,
                              hipStream_t stream) {
    const float* features = (const float*)d_in[0];   // [B,N,C] f32
    const int*   coords   = (const int*)d_in[1];     // [B,N,2] i32
    const float* w_ih     = (const float*)d_in[2];   // [512,16]
    const float* w_hh     = (const float*)d_in[3];   // [512,128]
    const float* b_ih     = (const float*)d_in[4];   // [512]
    const float* b_hh     = (const float*)d_in[5];   // [512]
    float* out = (float*)d_out;                      // [B,128,128,128]

    char* ws = (char*)d_ws;
    float* w_ih_T   = (float*)(ws + 0);              //    32768 B
    float* w_hh_T   = (float*)(ws + 32768);          //   262144 B
    float* biassum  = (float*)(ws + 294912);         //     2048 B
    int*   map      = (int*)(ws + 296960);           //   524288 B
    int*   cnt      = (int*)(ws + 821248);           //       64 B
    int*   m2cnt    = (int*)(ws + 821312);           //       64 B
    int*   m3cnt    = (int*)(ws + 821376);           //       64 B
    int*   chainpk  = (int*)(ws + 821440);           //    65536 B
    int*   mlist2   = (int*)(ws + 886976);           //    16384 B
    int*   mlist3   = (int*)(ws + 903360);           //     8192 B
    int*   slots    = (int*)(ws + 911552);           //  4194304 B
    float* hfin     = (float*)(ws + 5105856);        //  8388608 B -> ~13.5 MB

    k_pre<<<dim3(81), dim3(1024), 0, stream>>>(
        coords, w_ih, w_hh, b_ih, b_hh, w_ih_T, w_hh_T, biassum,
        map, cnt, m2cnt, m3cnt, chainpk, mlist2, mlist3, slots);
    k_main<<<dim3(1536), dim3(512), 0, stream>>>(
        features, w_ih_T, w_hh_T, biassum, cnt, chainpk, m2cnt, m3cnt,
        mlist2, mlist3, slots, hfin);
    k_scatter<<<dim3(B * 128), dim3(256), 0, stream>>>(hfin, map, out);
}